// Round 12
// baseline (83.686 us; speedup 1.0000x reference)
//
#include <hip/hip_runtime.h>
#include <math.h>

#define H 128
#define MUL 32
#define NC (5 * MUL * MUL)   // 5120 columns of R
#define NIV (H + 1)          // max intervals = 129
#define NMAX 4000
#define EPB 2                // edges per block
#define TILE4 4096           // float4 per 128x128 tile

typedef float f32x4 __attribute__((ext_vector_type(4)));

// Static device scratch. Recomputed every launch (deterministic).
__device__ float g_A[NIV * NC];      // norm-scaled: R_scaled = rad*A + B per interval
__device__ float g_B[NIV * NC];
__device__ float4 g_ey[NMAX];        // (Y0,Y1,Y2, radius)
__device__ int    g_eidx[NMAX];      // interval index, -1 => fallback (kernel2)

// ---------------- Fused prep. Cheap nbp count first; rank-sort ONLY if nbp>0.
__global__ __launch_bounds__(256) void prep_all(const float* __restrict__ W1,
                                                const float* __restrict__ b1,
                                                const float* __restrict__ W2,
                                                const float* __restrict__ b2,
                                                const float* __restrict__ r, int N) {
    __shared__ float bp[H];
    __shared__ float sorted[H];
    int tid = threadIdx.x;
    bool valid = false;
    float v = 3.0e38f;                   // invalid sentinel
    if (tid < H) {
        float a = W1[tid], b = b1[tid];
        if (a != 0.0f) {
            float t = -b / a;
            if (t > 0.0f) { v = t; valid = true; }   // only breakpoints in (0,inf)
        }
        bp[tid] = v;
    }
    int nbp = __syncthreads_count(valid);    // counts valid breakpoints; syncs bp[]
    int y = blockIdx.y;
    bool isEdge = (y == NIV);
    if (!isEdge && y > nbp) return;          // fast exit BEFORE the O(H^2) sort

    if (nbp > 0) {                           // rank sort only when breakpoints exist
        if (tid < H) {
            int rank = 0;
            #pragma unroll 8
            for (int j = 0; j < H; ++j) {
                float bj = bp[j];
                rank += (bj < v) || (bj == v && j < tid);
            }
            sorted[rank] = v;                // ranks form a permutation of 0..127
        }
        __syncthreads();
    }

    if (isEdge) {
        int e = blockIdx.x * 256 + tid;
        if (e >= N) return;
        float x = r[3 * e], yy = r[3 * e + 1], z = r[3 * e + 2];
        float rad = sqrtf(x * x + yy * yy + z * z);
        bool mask = rad > 0.1f;
        float inv = mask ? (1.7320508075688772f / rad) : 0.0f;   // sqrt(3)/rad
        g_ey[e] = make_float4(x * inv, yy * inv, z * inv, rad);
        int idx = -1;
        if (mask) {
            idx = 0;
            for (int j = 0; j < nbp; ++j) idx += (sorted[j] < rad) ? 1 : 0;
        }
        g_eidx[e] = idx;
        return;
    }

    // interval pass: representative radius for interval y
    float rm;
    if (nbp == 0)       rm = 1.0f;
    else if (y == 0)    rm = 0.5f * sorted[0];
    else if (y >= nbp)  rm = sorted[nbp - 1] + 1.0f;
    else                rm = 0.5f * (sorted[y - 1] + sorted[y]);

    int c = blockIdx.x * 256 + tid;
    float accA = 0.0f, accB = 0.0f;
    // unroll 32: ~32 independent W2 loads in flight; this 20-block pass gates
    // main's launch (proven on R11's unroll 4->16 = -1.7us). 16->32 halves the
    // remaining serialized round-trip groups.
    #pragma unroll 32
    for (int k = 0; k < H; ++k) {
        float a = W1[k], b = b1[k];
        float w2 = W2[k * NC + c];
        bool act = (a * rm + b) > 0.0f;      // relu gate, constant within interval y
        accA += act ? a * w2 : 0.0f;
        accB += act ? b * w2 : 0.0f;
    }
    // fold per-path norm: p0 -> n0, p1/p2 -> n1, p3/p4 -> ns
    int p = c >> 10;
    const float n0 = 0.125f;                  // 1/sqrt(2*MUL)
    const float n1 = 0.10206207261596575f;    // 1/sqrt(3*MUL)
    const float ns = 0.07216878364870323f;    // n0/sqrt(3) == n1/sqrt(2)
    float s = (p == 0) ? n0 : ((p <= 2) ? n1 : ns);
    g_A[y * NC + c] = s * accA;
    g_B[y * NC + c] = s * (accB + b2[c]);
}

// ---------------- Main: thread = one float4 tile position, EPB-edge unrolled loop.
// grid = (16 position-chunks, N/EPB), block = 256. Position constants hoisted once;
// EPB edges' uniforms preloaded to registers; loop body = VALU + nt f4 store.
// nt stores: proven +9us vs regular (R10 A/B). EPB=2: 32K blocks (R6->R7 trend).
__global__ __launch_bounds__(256) void main_kernel(const float* __restrict__ lin_w0,
                                                   const float* __restrict__ lin_w1,
                                                   float* __restrict__ out, int N) {
    int pos  = blockIdx.x * 256 + threadIdx.x;   // float4 index in 128x128 tile [0,4096)
    int row  = pos >> 5;                         // 0..127
    int col0 = (pos & 31) << 2;                  // 0..124

    const float s = 0.17677669529663687f;        // 1/sqrt(MUL)
    int   cidx[4]; int iY[4]; float sgn[4]; float fb[4];

    #pragma unroll
    for (int q = 0; q < 4; ++q) {
        int col = col0 + q;
        int ci, sel; float sg = 1.0f, f = 0.0f;
        if (row < MUL) {
            if (col < MUL) {                       // K00: p=0, [row, col]
                ci = row * MUL + col; sel = 3; f = s * lin_w0[row * MUL + col];
            } else {                               // K01: p=3, [row, u] * Y[i]
                int cc = col - MUL; int u = (cc * 171) >> 9; int i = cc - 3 * u;
                ci = 3 * 1024 + row * MUL + u; sel = i;
            }
        } else {
            int rr = row - MUL; int w = (rr * 171) >> 9; int j = rr - 3 * w;
            if (col < MUL) {                       // K10: p=2, [w, col] * Y[j]
                ci = 2 * 1024 + w * MUL + col; sel = j;
            } else {                               // K11
                int cc = col - MUL; int u = (cc * 171) >> 9; int i = cc - 3 * u;
                if (i == j) {                      // diag: p=1 (R0b)
                    ci = 1 * 1024 + w * MUL + u; sel = 3; f = s * lin_w1[w * MUL + u];
                } else {                           // off-diag: p=4, +-R1c * Y[k]
                    int jp = (j == 2) ? 0 : (j + 1);
                    ci = 4 * 1024 + w * MUL + u; sel = 3 - i - j;
                    sg = (i == jp) ? 1.0f : -1.0f;
                }
            }
        }
        cidx[q] = ci; iY[q] = sel; sgn[q] = sg; fb[q] = f;
    }

    int n0 = blockIdx.y * EPB;

    // preload EPB edges' uniforms into registers (static indexing -> no scratch)
    float4 eys[EPB]; int idxs[EPB];
    #pragma unroll
    for (int k = 0; k < EPB; ++k) {
        int n = n0 + k; if (n > N - 1) n = N - 1;
        eys[k] = g_ey[n];
        idxs[k] = g_eidx[n];
    }

    f32x4* base = reinterpret_cast<f32x4*>(out) + (size_t)n0 * TILE4 + pos;
    int cached = -2;
    float Ac[4], Bc[4];

    #pragma unroll
    for (int k = 0; k < EPB; ++k) {
        if (n0 + k >= N) break;
        int idx = idxs[k];
        float4 ey = eys[k];
        f32x4 v;
        if (idx >= 0) {
            if (idx != cached) {             // wave-uniform; at most once per idx run
                const float* __restrict__ Ab = g_A + (size_t)idx * NC;
                const float* __restrict__ Bb = g_B + (size_t)idx * NC;
                #pragma unroll
                for (int q = 0; q < 4; ++q) {
                    Ac[q] = sgn[q] * Ab[cidx[q]];
                    Bc[q] = sgn[q] * Bb[cidx[q]];
                }
                cached = idx;
            }
            float rad = ey.w;
            #pragma unroll
            for (int q = 0; q < 4; ++q) {
                float ys = (iY[q] == 0) ? ey.x : ((iY[q] == 1) ? ey.y
                         : ((iY[q] == 2) ? ey.z : 1.0f));
                v[q] = fmaf(rad, Ac[q], Bc[q]) * ys;
            }
        } else {
            #pragma unroll
            for (int q = 0; q < 4; ++q) v[q] = fb[q];
        }
        __builtin_nontemporal_store(v, base + (size_t)k * TILE4);
    }
}

extern "C" void kernel_launch(void* const* d_in, const int* in_sizes, int n_in,
                              void* d_out, int out_size, void* d_ws, size_t ws_size,
                              hipStream_t stream) {
    const float* r   = (const float*)d_in[0];
    const float* W1  = (const float*)d_in[1];
    const float* b1  = (const float*)d_in[2];
    const float* W2  = (const float*)d_in[3];
    const float* b2  = (const float*)d_in[4];
    const float* lw0 = (const float*)d_in[5];
    const float* lw1 = (const float*)d_in[6];
    float* out = (float*)d_out;
    int N = in_sizes[0] / 3;

    prep_all<<<dim3(NC / 256, NIV + 1), dim3(256), 0, stream>>>(W1, b1, W2, b2, r, N);
    int eChunks = (N + EPB - 1) / EPB;
    main_kernel<<<dim3(16, eChunks), dim3(256), 0, stream>>>(lw0, lw1, out, N);
}

// Round 13
// 57.103 us; speedup vs baseline: 1.4655x; 1.4655x over previous
//
#include <hip/hip_runtime.h>
#include <math.h>

#define H 128
#define MUL 32
#define NC (5 * MUL * MUL)   // 5120 columns of R
#define NIV (H + 1)          // max intervals = 129
#define NMAX 4000
#define EPB 4                // edges per block (empirical optimum, R7/R11 vs R6/R12)
#define TILE4 4096           // float4 per 128x128 tile

typedef float f32x4 __attribute__((ext_vector_type(4)));

// Static device scratch. Recomputed every launch (deterministic).
__device__ float g_A[NIV * NC];      // norm-scaled: R_scaled = rad*A + B per interval
__device__ float g_B[NIV * NC];
__device__ float4 g_ey[NMAX];        // (Y0,Y1,Y2, radius)
__device__ int    g_eidx[NMAX];      // interval index, -1 => fallback (kernel2)

// ---------------- Fused prep. Cheap nbp count first; rank-sort ONLY if nbp>0.
__global__ __launch_bounds__(256) void prep_all(const float* __restrict__ W1,
                                                const float* __restrict__ b1,
                                                const float* __restrict__ W2,
                                                const float* __restrict__ b2,
                                                const float* __restrict__ r, int N) {
    __shared__ float bp[H];
    __shared__ float sorted[H];
    int tid = threadIdx.x;
    bool valid = false;
    float v = 3.0e38f;                   // invalid sentinel
    if (tid < H) {
        float a = W1[tid], b = b1[tid];
        if (a != 0.0f) {
            float t = -b / a;
            if (t > 0.0f) { v = t; valid = true; }   // only breakpoints in (0,inf)
        }
        bp[tid] = v;
    }
    int nbp = __syncthreads_count(valid);    // counts valid breakpoints; syncs bp[]
    int y = blockIdx.y;
    bool isEdge = (y == NIV);
    if (!isEdge && y > nbp) return;          // fast exit BEFORE the O(H^2) sort

    if (nbp > 0) {                           // rank sort only when breakpoints exist
        if (tid < H) {
            int rank = 0;
            #pragma unroll 8
            for (int j = 0; j < H; ++j) {
                float bj = bp[j];
                rank += (bj < v) || (bj == v && j < tid);
            }
            sorted[rank] = v;                // ranks form a permutation of 0..127
        }
        __syncthreads();
    }

    if (isEdge) {
        int e = blockIdx.x * 256 + tid;
        if (e >= N) return;
        float x = r[3 * e], yy = r[3 * e + 1], z = r[3 * e + 2];
        float rad = sqrtf(x * x + yy * yy + z * z);
        bool mask = rad > 0.1f;
        float inv = mask ? (1.7320508075688772f / rad) : 0.0f;   // sqrt(3)/rad
        g_ey[e] = make_float4(x * inv, yy * inv, z * inv, rad);
        int idx = -1;
        if (mask) {
            idx = 0;
            for (int j = 0; j < nbp; ++j) idx += (sorted[j] < rad) ? 1 : 0;
        }
        g_eidx[e] = idx;
        return;
    }

    // interval pass: representative radius for interval y
    float rm;
    if (nbp == 0)       rm = 1.0f;
    else if (y == 0)    rm = 0.5f * sorted[0];
    else if (y >= nbp)  rm = sorted[nbp - 1] + 1.0f;
    else                rm = 0.5f * (sorted[y - 1] + sorted[y]);

    int c = blockIdx.x * 256 + tid;
    float accA = 0.0f, accB = 0.0f;
    // unroll 16: ~16 independent W2 loads in flight (R11-proven; 32 regressed in R12)
    #pragma unroll 16
    for (int k = 0; k < H; ++k) {
        float a = W1[k], b = b1[k];
        float w2 = W2[k * NC + c];
        bool act = (a * rm + b) > 0.0f;      // relu gate, constant within interval y
        accA += act ? a * w2 : 0.0f;
        accB += act ? b * w2 : 0.0f;
    }
    // fold per-path norm: p0 -> n0, p1/p2 -> n1, p3/p4 -> ns
    int p = c >> 10;
    const float n0 = 0.125f;                  // 1/sqrt(2*MUL)
    const float n1 = 0.10206207261596575f;    // 1/sqrt(3*MUL)
    const float ns = 0.07216878364870323f;    // n0/sqrt(3) == n1/sqrt(2)
    float s = (p == 0) ? n0 : ((p <= 2) ? n1 : ns);
    g_A[y * NC + c] = s * accA;
    g_B[y * NC + c] = s * (accB + b2[c]);
}

// ---------------- Main: thread = one float4 tile position, EPB-edge unrolled loop.
// grid = (16 position-chunks, N/EPB), block = 256. Position constants hoisted once;
// EPB edges' uniforms preloaded to registers; loop body = VALU + nt f4 store.
// nt stores: +9us vs regular (R10 A/B). Fallback lin-loads moved into the rare
// wave-uniform idx<0 branch (fallback edges are contiguous n<100) -> 97.5% of
// blocks skip those 4 global loads + VALU in the prologue.
__global__ __launch_bounds__(256) void main_kernel(const float* __restrict__ lin_w0,
                                                   const float* __restrict__ lin_w1,
                                                   float* __restrict__ out, int N) {
    int pos  = blockIdx.x * 256 + threadIdx.x;   // float4 index in 128x128 tile [0,4096)
    int row  = pos >> 5;                         // 0..127
    int col0 = (pos & 31) << 2;                  // 0..124

    int   cidx[4]; int iY[4]; float sgn[4];

    #pragma unroll
    for (int q = 0; q < 4; ++q) {
        int col = col0 + q;
        int ci, sel; float sg = 1.0f;
        if (row < MUL) {
            if (col < MUL) {                       // K00: p=0, [row, col]
                ci = row * MUL + col; sel = 3;
            } else {                               // K01: p=3, [row, u] * Y[i]
                int cc = col - MUL; int u = (cc * 171) >> 9; int i = cc - 3 * u;
                ci = 3 * 1024 + row * MUL + u; sel = i;
            }
        } else {
            int rr = row - MUL; int w = (rr * 171) >> 9; int j = rr - 3 * w;
            if (col < MUL) {                       // K10: p=2, [w, col] * Y[j]
                ci = 2 * 1024 + w * MUL + col; sel = j;
            } else {                               // K11
                int cc = col - MUL; int u = (cc * 171) >> 9; int i = cc - 3 * u;
                if (i == j) {                      // diag: p=1 (R0b)
                    ci = 1 * 1024 + w * MUL + u; sel = 3;
                } else {                           // off-diag: p=4, +-R1c * Y[k]
                    int jp = (j == 2) ? 0 : (j + 1);
                    ci = 4 * 1024 + w * MUL + u; sel = 3 - i - j;
                    sg = (i == jp) ? 1.0f : -1.0f;
                }
            }
        }
        cidx[q] = ci; iY[q] = sel; sgn[q] = sg;
    }

    int n0 = blockIdx.y * EPB;

    // preload EPB edges' uniforms into registers (static indexing -> no scratch)
    float4 eys[EPB]; int idxs[EPB];
    #pragma unroll
    for (int k = 0; k < EPB; ++k) {
        int n = n0 + k; if (n > N - 1) n = N - 1;
        eys[k] = g_ey[n];
        idxs[k] = g_eidx[n];
    }

    f32x4* base = reinterpret_cast<f32x4*>(out) + (size_t)n0 * TILE4 + pos;
    int cached = -2;
    float Ac[4], Bc[4];

    #pragma unroll
    for (int k = 0; k < EPB; ++k) {
        if (n0 + k >= N) break;
        int idx = idxs[k];
        float4 ey = eys[k];
        f32x4 v;
        if (idx >= 0) {
            if (idx != cached) {             // wave-uniform; at most once per idx run
                const float* __restrict__ Ab = g_A + (size_t)idx * NC;
                const float* __restrict__ Bb = g_B + (size_t)idx * NC;
                #pragma unroll
                for (int q = 0; q < 4; ++q) {
                    Ac[q] = sgn[q] * Ab[cidx[q]];
                    Bc[q] = sgn[q] * Bb[cidx[q]];
                }
                cached = idx;
            }
            float rad = ey.w;
            #pragma unroll
            for (int q = 0; q < 4; ++q) {
                float ys = (iY[q] == 0) ? ey.x : ((iY[q] == 1) ? ey.y
                         : ((iY[q] == 2) ? ey.z : 1.0f));
                v[q] = fmaf(rad, Ac[q], Bc[q]) * ys;
            }
        } else {
            // fallback KernelLinear (rare, wave-uniform): block-diag, 1/sqrt(MUL)
            const float s = 0.17677669529663687f;
            #pragma unroll
            for (int q = 0; q < 4; ++q) {
                int col = col0 + q;
                float f = 0.0f;
                if (row < MUL) {
                    if (col < MUL) f = s * lin_w0[row * MUL + col];
                } else if (col >= MUL) {
                    int rr = row - MUL; int w = (rr * 171) >> 9; int j = rr - 3 * w;
                    int cc = col - MUL; int u = (cc * 171) >> 9; int i = cc - 3 * u;
                    if (i == j) f = s * lin_w1[w * MUL + u];
                }
                v[q] = f;
            }
        }
        __builtin_nontemporal_store(v, base + (size_t)k * TILE4);
    }
}

extern "C" void kernel_launch(void* const* d_in, const int* in_sizes, int n_in,
                              void* d_out, int out_size, void* d_ws, size_t ws_size,
                              hipStream_t stream) {
    const float* r   = (const float*)d_in[0];
    const float* W1  = (const float*)d_in[1];
    const float* b1  = (const float*)d_in[2];
    const float* W2  = (const float*)d_in[3];
    const float* b2  = (const float*)d_in[4];
    const float* lw0 = (const float*)d_in[5];
    const float* lw1 = (const float*)d_in[6];
    float* out = (float*)d_out;
    int N = in_sizes[0] / 3;

    prep_all<<<dim3(NC / 256, NIV + 1), dim3(256), 0, stream>>>(W1, b1, W2, b2, r, N);
    int eChunks = (N + EPB - 1) / EPB;
    main_kernel<<<dim3(16, eChunks), dim3(256), 0, stream>>>(lw0, lw1, out, N);
}